// Round 4
// baseline (458.172 us; speedup 1.0000x reference)
//
#include <hip/hip_runtime.h>
#include <math.h>

// Problem constants (fixed by the reference)
#define L_SEQ   4096
#define DI      4096   // d_inner
#define RNK     128    // dt_rank
#define NS      16     // d_state
#define NCOL    160    // dt_rank + 2*d_state
#define GCH     32     // scan chunks
#define CLEN    128    // L_SEQ / GCH

// Workspace layout (floats):
//   [0, 4*655360)            : dbc K-split partials; slice 0 becomes final dbc [L,160]
//   [2621440, 2621440+32*32*4096) : chunk partials  [G][32][D]  (P in [0,16), H/h_in in [16,32))
// total = 6,815,744 floats = 27.3 MB  (d_out is reused as the 64MB delta buffer)
#define DBC_SLICE 655360
#define PART_OFF  2621440

__device__ __forceinline__ float fast_exp2(float v) {
#if __has_builtin(__builtin_amdgcn_exp2f)
  return __builtin_amdgcn_exp2f(v);
#else
  return exp2f(v);
#endif
}

// ---------------- GEMM1: dbc[l,j] = sum_k x[l,k] * W_in[j,k] ----------------
// grid 256: bx>>2 = m-tile (64 rows each), bx&3 = K slice (1024 each). block 256.
__global__ __launch_bounds__(256) void gemm1_kernel(const float* __restrict__ x,
                                                    const float* __restrict__ Win,
                                                    float* __restrict__ dbc_parts) {
  __shared__ float xs[64][68];    // +4 pad: lane bank stride 4 -> 2-way (free)
  __shared__ float wsh[160][68];
  const int t  = threadIdx.x;
  const int tx = t & 15, ty = t >> 4;
  const int mt = blockIdx.x >> 2;
  const int ks = blockIdx.x & 3;
  const int row0 = mt * 64;
  const int kbase0 = ks * 1024;

  float acc[4][10];
#pragma unroll
  for (int r = 0; r < 4; ++r)
#pragma unroll
    for (int c = 0; c < 10; ++c) acc[r][c] = 0.f;

  for (int kc = 0; kc < 16; ++kc) {
    const int kb = kbase0 + kc * 64;
#pragma unroll
    for (int i = 0; i < 4; ++i) {            // x tile: 64 rows x 64 k
      int f = t + i * 256;
      int r = f >> 4, c4 = (f & 15) * 4;
      *(float4*)&xs[r][c4] = *(const float4*)&x[(row0 + r) * 4096 + kb + c4];
    }
#pragma unroll
    for (int i = 0; i < 10; ++i) {           // W tile: 160 rows x 64 k
      int f = t + i * 256;
      int r = f >> 4, c4 = (f & 15) * 4;
      *(float4*)&wsh[r][c4] = *(const float4*)&Win[r * 4096 + kb + c4];
    }
    __syncthreads();
#pragma unroll
    for (int kk = 0; kk < 16; ++kk) {
      float4 xv[4];
#pragma unroll
      for (int r = 0; r < 4; ++r) xv[r] = *(float4*)&xs[ty * 4 + r][kk * 4];
#pragma unroll
      for (int c = 0; c < 10; ++c) {
        float4 wv = *(float4*)&wsh[tx + 16 * c][kk * 4];
#pragma unroll
        for (int r = 0; r < 4; ++r) {
          acc[r][c] = fmaf(xv[r].x, wv.x, acc[r][c]);
          acc[r][c] = fmaf(xv[r].y, wv.y, acc[r][c]);
          acc[r][c] = fmaf(xv[r].z, wv.z, acc[r][c]);
          acc[r][c] = fmaf(xv[r].w, wv.w, acc[r][c]);
        }
      }
    }
    __syncthreads();
  }
  float* outp = dbc_parts + ks * DBC_SLICE;
#pragma unroll
  for (int r = 0; r < 4; ++r)
#pragma unroll
    for (int c = 0; c < 10; ++c)
      outp[(row0 + ty * 4 + r) * NCOL + tx + 16 * c] = acc[r][c];
}

// ---------------- reduce the 4 K-slices into slice 0 ----------------
__global__ __launch_bounds__(256) void reduce_dbc_kernel(float* __restrict__ p) {
  const int i = (blockIdx.x * 256 + threadIdx.x) * 4;  // grid 640 -> covers 655360
  float4 a = *(float4*)&p[i];
  float4 b = *(float4*)&p[DBC_SLICE + i];
  float4 c = *(float4*)&p[2 * DBC_SLICE + i];
  float4 d = *(float4*)&p[3 * DBC_SLICE + i];
  a.x += b.x + c.x + d.x;
  a.y += b.y + c.y + d.y;
  a.z += b.z + c.z + d.z;
  a.w += b.w + c.w + d.w;
  *(float4*)&p[i] = a;
}

// ---- GEMM2 + softplus: delta[l,d] = softplus(sum_k dbc[l,k]*W_delta[d,k]) ----
// grid 1024 (32x32 tiles of 128x128), block 256, thread 8x8.
__global__ __launch_bounds__(256) void gemm2_kernel(const float* __restrict__ dbc,
                                                    const float* __restrict__ Wd,
                                                    float* __restrict__ delta_out) {
  __shared__ float as_[128][36];
  __shared__ float bs_[128][36];
  const int t  = threadIdx.x;
  const int tx = t & 15, ty = t >> 4;
  const int mt = blockIdx.x & 31, nt = blockIdx.x >> 5;

  float acc[8][8];
#pragma unroll
  for (int r = 0; r < 8; ++r)
#pragma unroll
    for (int c = 0; c < 8; ++c) acc[r][c] = 0.f;

  for (int kc = 0; kc < 4; ++kc) {
    const int kb = kc * 32;
#pragma unroll
    for (int i = 0; i < 4; ++i) {
      int f = t + i * 256;
      int r = f >> 3, c4 = (f & 7) * 4;
      *(float4*)&as_[r][c4] = *(const float4*)&dbc[(mt * 128 + r) * NCOL + kb + c4];
      *(float4*)&bs_[r][c4] = *(const float4*)&Wd[(nt * 128 + r) * RNK + kb + c4];
    }
    __syncthreads();
#pragma unroll
    for (int kk = 0; kk < 8; ++kk) {
      float4 av[8];
#pragma unroll
      for (int r = 0; r < 8; ++r) av[r] = *(float4*)&as_[ty + 16 * r][kk * 4];
#pragma unroll
      for (int c = 0; c < 8; ++c) {
        float4 bv = *(float4*)&bs_[tx + 16 * c][kk * 4];
#pragma unroll
        for (int r = 0; r < 8; ++r) {
          acc[r][c] = fmaf(av[r].x, bv.x, acc[r][c]);
          acc[r][c] = fmaf(av[r].y, bv.y, acc[r][c]);
          acc[r][c] = fmaf(av[r].z, bv.z, acc[r][c]);
          acc[r][c] = fmaf(av[r].w, bv.w, acc[r][c]);
        }
      }
    }
    __syncthreads();
  }
#pragma unroll
  for (int r = 0; r < 8; ++r) {
    const int row = mt * 128 + ty + 16 * r;
#pragma unroll
    for (int c = 0; c < 8; ++c) {
      float v = acc[r][c];
      float sp = (v > 20.f) ? v : log1pf(__expf(v));   // stable softplus
      delta_out[row * 4096 + nt * 128 + tx + 16 * c] = sp;
    }
  }
}

// ---------------- scan pass 1: per-chunk P (cumprod dA) and H (zero-init state) ----------------
// grid (16, 32): x = d-tile of 256 channels, y = chunk. block 256 (1 thread = 1 channel).
__global__ __launch_bounds__(256) void scan1_kernel(const float* __restrict__ delta,
                                                    const float* __restrict__ x,
                                                    const float* __restrict__ A_log,
                                                    const float* __restrict__ dbc,
                                                    float* __restrict__ part) {
  __shared__ float Bs[CLEN][NS];
  const int t = threadIdx.x;
  const int d = blockIdx.x * 256 + t;
  const int g = blockIdx.y;
  const int l0 = g * CLEN;
#pragma unroll
  for (int i = 0; i < 8; ++i) {
    int f = t + i * 256;
    int l = f >> 4, n = f & 15;
    Bs[l][n] = dbc[(l0 + l) * NCOL + RNK + n];
  }
  __syncthreads();

  float al2[NS];
#pragma unroll
  for (int n = 0; n < NS; ++n) al2[n] = -expf(A_log[d * NS + n]) * 1.44269504f;
  bool uni = true;
#pragma unroll
  for (int n = 1; n < NS; ++n) uni = uni && (al2[n] == al2[0]);

  float h[NS], P[NS];
#pragma unroll
  for (int n = 0; n < NS; ++n) { h[n] = 0.f; P[n] = 1.f; }

  if (uni) {   // all 16 A values identical for this channel (true for this init) -> 1 exp/step
    const float a0 = al2[0];
    float Ps = 1.f;
    for (int l = 0; l < CLEN; ++l) {
      float dv = delta[(l0 + l) * 4096 + d];
      float xv = x[(l0 + l) * 4096 + d];
      float dx = dv * xv;
      float dA = fast_exp2(dv * a0);
      Ps *= dA;
      const float4* br = (const float4*)Bs[l];
      float4 b0 = br[0], b1 = br[1], b2 = br[2], b3 = br[3];
      h[0]  = fmaf(dA, h[0],  dx * b0.x); h[1]  = fmaf(dA, h[1],  dx * b0.y);
      h[2]  = fmaf(dA, h[2],  dx * b0.z); h[3]  = fmaf(dA, h[3],  dx * b0.w);
      h[4]  = fmaf(dA, h[4],  dx * b1.x); h[5]  = fmaf(dA, h[5],  dx * b1.y);
      h[6]  = fmaf(dA, h[6],  dx * b1.z); h[7]  = fmaf(dA, h[7],  dx * b1.w);
      h[8]  = fmaf(dA, h[8],  dx * b2.x); h[9]  = fmaf(dA, h[9],  dx * b2.y);
      h[10] = fmaf(dA, h[10], dx * b2.z); h[11] = fmaf(dA, h[11], dx * b2.w);
      h[12] = fmaf(dA, h[12], dx * b3.x); h[13] = fmaf(dA, h[13], dx * b3.y);
      h[14] = fmaf(dA, h[14], dx * b3.z); h[15] = fmaf(dA, h[15], dx * b3.w);
    }
#pragma unroll
    for (int n = 0; n < NS; ++n) P[n] = Ps;
  } else {     // generic path: 16 exps/step
    for (int l = 0; l < CLEN; ++l) {
      float dv = delta[(l0 + l) * 4096 + d];
      float xv = x[(l0 + l) * 4096 + d];
      float dx = dv * xv;
#pragma unroll
      for (int n = 0; n < NS; ++n) {
        float dA = fast_exp2(dv * al2[n]);
        h[n] = fmaf(dA, h[n], dx * Bs[l][n]);
        P[n] *= dA;
      }
    }
  }
  float* pg = part + (size_t)g * 32 * 4096;
#pragma unroll
  for (int n = 0; n < NS; ++n) {
    pg[n * 4096 + d] = P[n];
    pg[(NS + n) * 4096 + d] = h[n];
  }
}

// ---------------- scan pass 2: combine chunks; P-slot becomes h_in (state before chunk) ----------------
__global__ __launch_bounds__(256) void scan2_kernel(float* __restrict__ part) {
  const int idx = blockIdx.x * 256 + threadIdx.x;  // grid 256 -> 65536 = D*NS
  const int d = idx & 4095;
  const int n = idx >> 12;
  float h = 0.f;
  for (int g = 0; g < GCH; ++g) {
    float* pg = part + (size_t)g * 32 * 4096;
    float Pv = pg[n * 4096 + d];
    float Hv = pg[(NS + n) * 4096 + d];
    float nh = fmaf(Pv, h, Hv);
    pg[n * 4096 + d] = h;   // h_in for chunk g
    h = nh;
  }
}

// ---------------- scan pass 3: recompute local scan with h_in, produce output ----------------
// io aliases delta (read) and out (write) -- same element, read-before-write per thread.
__global__ __launch_bounds__(256) void scan3_kernel(float* io,
                                                    const float* __restrict__ x,
                                                    const float* __restrict__ A_log,
                                                    const float* __restrict__ dbc,
                                                    const float* __restrict__ Dvec,
                                                    const float* __restrict__ part) {
  __shared__ float Bs[CLEN][NS];
  __shared__ float Cs[CLEN][NS];
  const int t = threadIdx.x;
  const int d = blockIdx.x * 256 + t;
  const int g = blockIdx.y;
  const int l0 = g * CLEN;
#pragma unroll
  for (int i = 0; i < 8; ++i) {
    int f = t + i * 256;
    int l = f >> 4, n = f & 15;
    Bs[l][n] = dbc[(l0 + l) * NCOL + RNK + n];
    Cs[l][n] = dbc[(l0 + l) * NCOL + RNK + NS + n];
  }
  __syncthreads();

  float al2[NS];
#pragma unroll
  for (int n = 0; n < NS; ++n) al2[n] = -expf(A_log[d * NS + n]) * 1.44269504f;
  bool uni = true;
#pragma unroll
  for (int n = 1; n < NS; ++n) uni = uni && (al2[n] == al2[0]);

  float h[NS];
  const float* pg = part + (size_t)g * 32 * 4096;
#pragma unroll
  for (int n = 0; n < NS; ++n) h[n] = pg[n * 4096 + d];
  const float Dd = Dvec[d];

  if (uni) {
    const float a0 = al2[0];
    for (int l = 0; l < CLEN; ++l) {
      float dv = io[(size_t)(l0 + l) * 4096 + d];
      float xv = x[(l0 + l) * 4096 + d];
      float dx = dv * xv;
      float dA = fast_exp2(dv * a0);
      const float4* br = (const float4*)Bs[l];
      const float4* cr = (const float4*)Cs[l];
      float4 b0 = br[0], b1 = br[1], b2 = br[2], b3 = br[3];
      float4 c0 = cr[0], c1 = cr[1], c2 = cr[2], c3 = cr[3];
      float y = 0.f;
      h[0]  = fmaf(dA, h[0],  dx * b0.x); y = fmaf(h[0],  c0.x, y);
      h[1]  = fmaf(dA, h[1],  dx * b0.y); y = fmaf(h[1],  c0.y, y);
      h[2]  = fmaf(dA, h[2],  dx * b0.z); y = fmaf(h[2],  c0.z, y);
      h[3]  = fmaf(dA, h[3],  dx * b0.w); y = fmaf(h[3],  c0.w, y);
      h[4]  = fmaf(dA, h[4],  dx * b1.x); y = fmaf(h[4],  c1.x, y);
      h[5]  = fmaf(dA, h[5],  dx * b1.y); y = fmaf(h[5],  c1.y, y);
      h[6]  = fmaf(dA, h[6],  dx * b1.z); y = fmaf(h[6],  c1.z, y);
      h[7]  = fmaf(dA, h[7],  dx * b1.w); y = fmaf(h[7],  c1.w, y);
      h[8]  = fmaf(dA, h[8],  dx * b2.x); y = fmaf(h[8],  c2.x, y);
      h[9]  = fmaf(dA, h[9],  dx * b2.y); y = fmaf(h[9],  c2.y, y);
      h[10] = fmaf(dA, h[10], dx * b2.z); y = fmaf(h[10], c2.z, y);
      h[11] = fmaf(dA, h[11], dx * b2.w); y = fmaf(h[11], c2.w, y);
      h[12] = fmaf(dA, h[12], dx * b3.x); y = fmaf(h[12], c3.x, y);
      h[13] = fmaf(dA, h[13], dx * b3.y); y = fmaf(h[13], c3.y, y);
      h[14] = fmaf(dA, h[14], dx * b3.z); y = fmaf(h[14], c3.z, y);
      h[15] = fmaf(dA, h[15], dx * b3.w); y = fmaf(h[15], c3.w, y);
      io[(size_t)(l0 + l) * 4096 + d] = fmaf(xv, Dd, y);
    }
  } else {
    for (int l = 0; l < CLEN; ++l) {
      float dv = io[(size_t)(l0 + l) * 4096 + d];
      float xv = x[(l0 + l) * 4096 + d];
      float dx = dv * xv;
      float y = 0.f;
#pragma unroll
      for (int n = 0; n < NS; ++n) {
        float dA = fast_exp2(dv * al2[n]);
        h[n] = fmaf(dA, h[n], dx * Bs[l][n]);
        y = fmaf(h[n], Cs[l][n], y);
      }
      io[(size_t)(l0 + l) * 4096 + d] = fmaf(xv, Dd, y);
    }
  }
}

extern "C" void kernel_launch(void* const* d_in, const int* in_sizes, int n_in,
                              void* d_out, int out_size, void* d_ws, size_t ws_size,
                              hipStream_t stream) {
  const float* x    = (const float*)d_in[0];
  const float* Win  = (const float*)d_in[1];
  const float* Wd   = (const float*)d_in[2];
  const float* Alog = (const float*)d_in[3];
  const float* Dv   = (const float*)d_in[4];
  float* out = (float*)d_out;          // reused as delta [L,D] between gemm2 and scan3
  float* ws  = (float*)d_ws;           // needs 27.3 MB
  float* dbc  = ws;
  float* part = ws + PART_OFF;

  gemm1_kernel<<<256, 256, 0, stream>>>(x, Win, dbc);
  reduce_dbc_kernel<<<640, 256, 0, stream>>>(dbc);
  gemm2_kernel<<<1024, 256, 0, stream>>>(dbc, Wd, out);
  scan1_kernel<<<dim3(16, 32), 256, 0, stream>>>(out, x, Alog, dbc, part);
  scan2_kernel<<<256, 256, 0, stream>>>(part);
  scan3_kernel<<<dim3(16, 32), 256, 0, stream>>>(out, x, Alog, dbc, Dv, part);
}

// Round 6
// 417.788 us; speedup vs baseline: 1.0967x; 1.0967x over previous
//
#include <hip/hip_runtime.h>
#include <math.h>

// Problem constants (fixed by the reference)
#define L_SEQ   4096
#define DI      4096   // d_inner
#define RNK     128    // dt_rank
#define NS      16     // d_state
#define NCOL    160    // dt_rank + 2*d_state
#define GCH     32     // scan chunks
#define CLEN    128    // L_SEQ / GCH
#define KSPLIT  16     // gemm1 K slices

// Buffers:
//   d_out (64 MB) triple-duty: gemm1 partials (16 x 2.6 MB) -> delta [L,D] -> output [L,D]
//   ws: [0, 655360) final dbc [L,160]; [655360, +4194304) chunk partials [G][32][D]
//       total 19.4 MB
#define DBC_SLICE 655360
#define PART_OFF  655360

__device__ __forceinline__ float fast_exp2(float v) {
#if __has_builtin(__builtin_amdgcn_exp2f)
  return __builtin_amdgcn_exp2f(v);
#else
  return exp2f(v);
#endif
}

// ---------------- GEMM1: dbc[l,j] = sum_k x[l,k] * W_in[j,k] ----------------
// grid 1024: bx>>4 = m-tile (64 rows), bx&15 = K slice (256 K each, 8 chunks of 32).
// LDS 32256 B -> 5 blocks/CU allowed; grid gives 4/CU -> ~16 waves/CU.
__global__ __launch_bounds__(256) void gemm1_kernel(const float* __restrict__ x,
                                                    const float* __restrict__ Win,
                                                    float* __restrict__ parts) {
  __shared__ float xs[64][36];
  __shared__ float wsh[160][36];
  const int t  = threadIdx.x;
  const int tx = t & 15, ty = t >> 4;
  const int mt = blockIdx.x >> 4;
  const int ks = blockIdx.x & 15;
  const int row0 = mt * 64;
  const int kbase0 = ks * 256;

  float acc[4][10];
#pragma unroll
  for (int r = 0; r < 4; ++r)
#pragma unroll
    for (int c = 0; c < 10; ++c) acc[r][c] = 0.f;

  for (int kc = 0; kc < 8; ++kc) {
    const int kb = kbase0 + kc * 32;
#pragma unroll
    for (int i = 0; i < 2; ++i) {            // x tile: 64 rows x 32 k = 512 float4
      int f = t + i * 256;
      int r = f >> 3, c4 = (f & 7) * 4;
      *(float4*)&xs[r][c4] = *(const float4*)&x[(row0 + r) * 4096 + kb + c4];
    }
#pragma unroll
    for (int i = 0; i < 5; ++i) {            // W tile: 160 rows x 32 k = 1280 float4
      int f = t + i * 256;
      int r = f >> 3, c4 = (f & 7) * 4;
      *(float4*)&wsh[r][c4] = *(const float4*)&Win[r * 4096 + kb + c4];
    }
    __syncthreads();
#pragma unroll
    for (int kk = 0; kk < 8; ++kk) {
      float4 xv[4];
#pragma unroll
      for (int r = 0; r < 4; ++r) xv[r] = *(float4*)&xs[ty * 4 + r][kk * 4];
#pragma unroll
      for (int c = 0; c < 10; ++c) {
        float4 wv = *(float4*)&wsh[tx + 16 * c][kk * 4];
#pragma unroll
        for (int r = 0; r < 4; ++r) {
          acc[r][c] = fmaf(xv[r].x, wv.x, acc[r][c]);
          acc[r][c] = fmaf(xv[r].y, wv.y, acc[r][c]);
          acc[r][c] = fmaf(xv[r].z, wv.z, acc[r][c]);
          acc[r][c] = fmaf(xv[r].w, wv.w, acc[r][c]);
        }
      }
    }
    __syncthreads();
  }
  float* outp = parts + ks * DBC_SLICE;
#pragma unroll
  for (int r = 0; r < 4; ++r)
#pragma unroll
    for (int c = 0; c < 10; ++c)
      outp[(row0 + ty * 4 + r) * NCOL + tx + 16 * c] = acc[r][c];
}

// ---------------- reduce the 16 K-slices (in d_out scratch) into ws dbc ----------------
__global__ __launch_bounds__(256) void reduce_dbc_kernel(const float* __restrict__ parts,
                                                         float* __restrict__ dbc) {
  const int i = (blockIdx.x * 256 + threadIdx.x) * 4;  // grid 640 -> covers 655360
  float4 a = *(const float4*)&parts[i];
#pragma unroll
  for (int s = 1; s < KSPLIT; ++s) {
    float4 b = *(const float4*)&parts[(size_t)s * DBC_SLICE + i];
    a.x += b.x; a.y += b.y; a.z += b.z; a.w += b.w;
  }
  *(float4*)&dbc[i] = a;
}

// ---- GEMM2 + softplus: delta[l,d] = softplus(sum_k dbc[l,k]*W_delta[d,k]) ----
// grid 1024 (32x32 tiles of 128x128), block 256, thread 8x8.
__global__ __launch_bounds__(256) void gemm2_kernel(const float* __restrict__ dbc,
                                                    const float* __restrict__ Wd,
                                                    float* __restrict__ delta_out) {
  __shared__ float as_[128][36];
  __shared__ float bs_[128][36];
  const int t  = threadIdx.x;
  const int tx = t & 15, ty = t >> 4;
  const int mt = blockIdx.x & 31, nt = blockIdx.x >> 5;

  float acc[8][8];
#pragma unroll
  for (int r = 0; r < 8; ++r)
#pragma unroll
    for (int c = 0; c < 8; ++c) acc[r][c] = 0.f;

  for (int kc = 0; kc < 4; ++kc) {
    const int kb = kc * 32;
#pragma unroll
    for (int i = 0; i < 4; ++i) {
      int f = t + i * 256;
      int r = f >> 3, c4 = (f & 7) * 4;
      *(float4*)&as_[r][c4] = *(const float4*)&dbc[(mt * 128 + r) * NCOL + kb + c4];
      *(float4*)&bs_[r][c4] = *(const float4*)&Wd[(nt * 128 + r) * RNK + kb + c4];
    }
    __syncthreads();
#pragma unroll
    for (int kk = 0; kk < 8; ++kk) {
      float4 av[8];
#pragma unroll
      for (int r = 0; r < 8; ++r) av[r] = *(float4*)&as_[ty + 16 * r][kk * 4];
#pragma unroll
      for (int c = 0; c < 8; ++c) {
        float4 bv = *(float4*)&bs_[tx + 16 * c][kk * 4];
#pragma unroll
        for (int r = 0; r < 8; ++r) {
          acc[r][c] = fmaf(av[r].x, bv.x, acc[r][c]);
          acc[r][c] = fmaf(av[r].y, bv.y, acc[r][c]);
          acc[r][c] = fmaf(av[r].z, bv.z, acc[r][c]);
          acc[r][c] = fmaf(av[r].w, bv.w, acc[r][c]);
        }
      }
    }
    __syncthreads();
  }
#pragma unroll
  for (int r = 0; r < 8; ++r) {
    const int row = mt * 128 + ty + 16 * r;
#pragma unroll
    for (int c = 0; c < 8; ++c) {
      float v = acc[r][c];
      float sp = (v > 20.f) ? v : log1pf(__expf(v));   // stable softplus
      delta_out[row * 4096 + nt * 128 + tx + 16 * c] = sp;
    }
  }
}

// ---------------- scan pass 1: per-chunk P (cumprod dA) and H (zero-init state) ----------------
// grid (16, 32): x = d-tile of 256 channels, y = chunk. block 256 (1 thread = 1 channel).
__global__ __launch_bounds__(256) void scan1_kernel(const float* __restrict__ delta,
                                                    const float* __restrict__ x,
                                                    const float* __restrict__ A_log,
                                                    const float* __restrict__ dbc,
                                                    float* __restrict__ part) {
  __shared__ float Bs[CLEN][NS];
  const int t = threadIdx.x;
  const int d = blockIdx.x * 256 + t;
  const int g = blockIdx.y;
  const int l0 = g * CLEN;
#pragma unroll
  for (int i = 0; i < 8; ++i) {
    int f = t + i * 256;
    int l = f >> 4, n = f & 15;
    Bs[l][n] = dbc[(l0 + l) * NCOL + RNK + n];
  }
  __syncthreads();

  float al2[NS];
#pragma unroll
  for (int n = 0; n < NS; ++n) al2[n] = -expf(A_log[d * NS + n]) * 1.44269504f;
  bool uni = true;
#pragma unroll
  for (int n = 1; n < NS; ++n) uni = uni && (al2[n] == al2[0]);

  float h[NS], P[NS];
#pragma unroll
  for (int n = 0; n < NS; ++n) { h[n] = 0.f; P[n] = 1.f; }

  if (uni) {   // all 16 A values identical for this channel (true for this init) -> 1 exp/step
    const float a0 = al2[0];
    float Ps = 1.f;
    for (int l = 0; l < CLEN; ++l) {
      float dv = delta[(l0 + l) * 4096 + d];
      float xv = x[(l0 + l) * 4096 + d];
      float dx = dv * xv;
      float dA = fast_exp2(dv * a0);
      Ps *= dA;
      const float4* br = (const float4*)Bs[l];
      float4 b0 = br[0], b1 = br[1], b2 = br[2], b3 = br[3];
      h[0]  = fmaf(dA, h[0],  dx * b0.x); h[1]  = fmaf(dA, h[1],  dx * b0.y);
      h[2]  = fmaf(dA, h[2],  dx * b0.z); h[3]  = fmaf(dA, h[3],  dx * b0.w);
      h[4]  = fmaf(dA, h[4],  dx * b1.x); h[5]  = fmaf(dA, h[5],  dx * b1.y);
      h[6]  = fmaf(dA, h[6],  dx * b1.z); h[7]  = fmaf(dA, h[7],  dx * b1.w);
      h[8]  = fmaf(dA, h[8],  dx * b2.x); h[9]  = fmaf(dA, h[9],  dx * b2.y);
      h[10] = fmaf(dA, h[10], dx * b2.z); h[11] = fmaf(dA, h[11], dx * b2.w);
      h[12] = fmaf(dA, h[12], dx * b3.x); h[13] = fmaf(dA, h[13], dx * b3.y);
      h[14] = fmaf(dA, h[14], dx * b3.z); h[15] = fmaf(dA, h[15], dx * b3.w);
    }
#pragma unroll
    for (int n = 0; n < NS; ++n) P[n] = Ps;
  } else {     // generic path: 16 exps/step
    for (int l = 0; l < CLEN; ++l) {
      float dv = delta[(l0 + l) * 4096 + d];
      float xv = x[(l0 + l) * 4096 + d];
      float dx = dv * xv;
#pragma unroll
      for (int n = 0; n < NS; ++n) {
        float dA = fast_exp2(dv * al2[n]);
        h[n] = fmaf(dA, h[n], dx * Bs[l][n]);
        P[n] *= dA;
      }
    }
  }
  float* pg = part + (size_t)g * 32 * 4096;
#pragma unroll
  for (int n = 0; n < NS; ++n) {
    pg[n * 4096 + d] = P[n];
    pg[(NS + n) * 4096 + d] = h[n];
  }
}

// ---------------- scan pass 2: combine chunks; P-slot becomes h_in (state before chunk) ----------------
__global__ __launch_bounds__(256) void scan2_kernel(float* __restrict__ part) {
  const int idx = blockIdx.x * 256 + threadIdx.x;  // grid 256 -> 65536 = D*NS
  const int d = idx & 4095;
  const int n = idx >> 12;
  float h = 0.f;
  for (int g = 0; g < GCH; ++g) {
    float* pg = part + (size_t)g * 32 * 4096;
    float Pv = pg[n * 4096 + d];
    float Hv = pg[(NS + n) * 4096 + d];
    float nh = fmaf(Pv, h, Hv);
    pg[n * 4096 + d] = h;   // h_in for chunk g
    h = nh;
  }
}

// ---------------- scan pass 3: recompute local scan with h_in, produce output ----------------
// io aliases delta (read) and out (write) -- same element, read-before-write per thread.
__global__ __launch_bounds__(256) void scan3_kernel(float* io,
                                                    const float* __restrict__ x,
                                                    const float* __restrict__ A_log,
                                                    const float* __restrict__ dbc,
                                                    const float* __restrict__ Dvec,
                                                    const float* __restrict__ part) {
  __shared__ float Bs[CLEN][NS];
  __shared__ float Cs[CLEN][NS];
  const int t = threadIdx.x;
  const int d = blockIdx.x * 256 + t;
  const int g = blockIdx.y;
  const int l0 = g * CLEN;
#pragma unroll
  for (int i = 0; i < 8; ++i) {
    int f = t + i * 256;
    int l = f >> 4, n = f & 15;
    Bs[l][n] = dbc[(l0 + l) * NCOL + RNK + n];
    Cs[l][n] = dbc[(l0 + l) * NCOL + RNK + NS + n];
  }
  __syncthreads();

  float al2[NS];
#pragma unroll
  for (int n = 0; n < NS; ++n) al2[n] = -expf(A_log[d * NS + n]) * 1.44269504f;
  bool uni = true;
#pragma unroll
  for (int n = 1; n < NS; ++n) uni = uni && (al2[n] == al2[0]);

  float h[NS];
  const float* pg = part + (size_t)g * 32 * 4096;
#pragma unroll
  for (int n = 0; n < NS; ++n) h[n] = pg[n * 4096 + d];
  const float Dd = Dvec[d];

  if (uni) {
    const float a0 = al2[0];
    for (int l = 0; l < CLEN; ++l) {
      float dv = io[(size_t)(l0 + l) * 4096 + d];
      float xv = x[(l0 + l) * 4096 + d];
      float dx = dv * xv;
      float dA = fast_exp2(dv * a0);
      const float4* br = (const float4*)Bs[l];
      const float4* cr = (const float4*)Cs[l];
      float4 b0 = br[0], b1 = br[1], b2 = br[2], b3 = br[3];
      float4 c0 = cr[0], c1 = cr[1], c2 = cr[2], c3 = cr[3];
      float y = 0.f;
      h[0]  = fmaf(dA, h[0],  dx * b0.x); y = fmaf(h[0],  c0.x, y);
      h[1]  = fmaf(dA, h[1],  dx * b0.y); y = fmaf(h[1],  c0.y, y);
      h[2]  = fmaf(dA, h[2],  dx * b0.z); y = fmaf(h[2],  c0.z, y);
      h[3]  = fmaf(dA, h[3],  dx * b0.w); y = fmaf(h[3],  c0.w, y);
      h[4]  = fmaf(dA, h[4],  dx * b1.x); y = fmaf(h[4],  c1.x, y);
      h[5]  = fmaf(dA, h[5],  dx * b1.y); y = fmaf(h[5],  c1.y, y);
      h[6]  = fmaf(dA, h[6],  dx * b1.z); y = fmaf(h[6],  c1.z, y);
      h[7]  = fmaf(dA, h[7],  dx * b1.w); y = fmaf(h[7],  c1.w, y);
      h[8]  = fmaf(dA, h[8],  dx * b2.x); y = fmaf(h[8],  c2.x, y);
      h[9]  = fmaf(dA, h[9],  dx * b2.y); y = fmaf(h[9],  c2.y, y);
      h[10] = fmaf(dA, h[10], dx * b2.z); y = fmaf(h[10], c2.z, y);
      h[11] = fmaf(dA, h[11], dx * b2.w); y = fmaf(h[11], c2.w, y);
      h[12] = fmaf(dA, h[12], dx * b3.x); y = fmaf(h[12], c3.x, y);
      h[13] = fmaf(dA, h[13], dx * b3.y); y = fmaf(h[13], c3.y, y);
      h[14] = fmaf(dA, h[14], dx * b3.z); y = fmaf(h[14], c3.z, y);
      h[15] = fmaf(dA, h[15], dx * b3.w); y = fmaf(h[15], c3.w, y);
      io[(size_t)(l0 + l) * 4096 + d] = fmaf(xv, Dd, y);
    }
  } else {
    for (int l = 0; l < CLEN; ++l) {
      float dv = io[(size_t)(l0 + l) * 4096 + d];
      float xv = x[(l0 + l) * 4096 + d];
      float dx = dv * xv;
      float y = 0.f;
#pragma unroll
      for (int n = 0; n < NS; ++n) {
        float dA = fast_exp2(dv * al2[n]);
        h[n] = fmaf(dA, h[n], dx * Bs[l][n]);
        y = fmaf(h[n], Cs[l][n], y);
      }
      io[(size_t)(l0 + l) * 4096 + d] = fmaf(xv, Dd, y);
    }
  }
}

extern "C" void kernel_launch(void* const* d_in, const int* in_sizes, int n_in,
                              void* d_out, int out_size, void* d_ws, size_t ws_size,
                              hipStream_t stream) {
  const float* x    = (const float*)d_in[0];
  const float* Win  = (const float*)d_in[1];
  const float* Wd   = (const float*)d_in[2];
  const float* Alog = (const float*)d_in[3];
  const float* Dv   = (const float*)d_in[4];
  float* out = (float*)d_out;          // scratch for gemm1 partials, then delta, then output
  float* ws  = (float*)d_ws;           // 19.4 MB
  float* dbc  = ws;
  float* part = ws + PART_OFF;

  gemm1_kernel<<<1024, 256, 0, stream>>>(x, Win, out);          // partials -> d_out
  reduce_dbc_kernel<<<640, 256, 0, stream>>>(out, dbc);         // final dbc -> ws
  gemm2_kernel<<<1024, 256, 0, stream>>>(dbc, Wd, out);         // delta -> d_out
  scan1_kernel<<<dim3(16, 32), 256, 0, stream>>>(out, x, Alog, dbc, part);
  scan2_kernel<<<256, 256, 0, stream>>>(part);
  scan3_kernel<<<dim3(16, 32), 256, 0, stream>>>(out, x, Alog, dbc, Dv, part);
}